// Round 4
// baseline (57.400 us; speedup 1.0000x reference)
//
#include <hip/hip_runtime.h>

// AdditiveAttention: B=2,H=8,Q=512,K=512,D=64
//   scores[b,h,q,k] = V_b + sum_d V_w[d]*tanh(q_proj[q,d] + k_proj[k,d])
//
// tanh(x) = 1 - 2/(1+e^{2x}),  e^{2(qp+kp)} = eq * (1/hk)
//   eq = exp2(C*qp), hk = exp2(-C*kp), C = 2*log2(e)
// score = (Vb + sum(Vw)) - 2 * sum_d (Vw[d]*hk[d]) / (hk[d] + eq[d])
// Pairwise rcp: v0/A + v1/B = (v0*B + v1*A) * rcp(A*B) -> 1 trans / 2 elems.

#define BHX 16
#define SEQ 512
#define DDIM 64
#define QT 32   // q rows per block (8 per wave)
#define KT 64   // k columns per block (= lanes)

// Both projections in one launch. blocks 0..511: query->eq, 512..1023: keys->hk.
__global__ __launch_bounds__(256) void proj_kernel(
    const float* __restrict__ query, const float* __restrict__ keys,
    const float* __restrict__ Wa_w,  const float* __restrict__ Wa_b,
    const float* __restrict__ Ua_w,  const float* __restrict__ Ua_b,
    float* __restrict__ eq, float* __restrict__ hk)
{
  const int t = threadIdx.x, lane = t & 63, wave = t >> 6;
  const bool is_k = blockIdx.x >= 512;
  const float* __restrict__ X  = is_k ? keys : query;
  const float* __restrict__ W  = is_k ? Ua_w : Wa_w;
  const float* __restrict__ Bv = is_k ? Ua_b : Wa_b;
  float* __restrict__ out      = is_k ? hk : eq;
  const int row0 = (blockIdx.x & 511) * 16;

  float w[64];
  const float4* W4 = (const float4*)(W + lane * DDIM);
#pragma unroll
  for (int i = 0; i < 16; ++i) {
    float4 v = W4[i];
    w[4*i] = v.x; w[4*i+1] = v.y; w[4*i+2] = v.z; w[4*i+3] = v.w;
  }
#pragma unroll
  for (int i = 0; i < 16; ++i)
    asm volatile("" : "+v"(w[4*i]), "+v"(w[4*i+1]), "+v"(w[4*i+2]), "+v"(w[4*i+3]));

  const float C = 2.885390081777926815f;          // 2*log2(e)
  const float b = Bv[lane];
  const float sgn = is_k ? -C : C;

#pragma unroll 1
  for (int i = 0; i < 4; ++i) {
    const int r   = row0 + wave * 4 + i;
    const int off = __builtin_amdgcn_readfirstlane(r * DDIM);
    const float* xr = X + off;                    // wave-uniform -> s_load
    float a0 = 0, a1 = 0, a2 = 0, a3 = 0;
#pragma unroll
    for (int e = 0; e < 64; e += 4) {
      a0 = __builtin_fmaf(xr[e],     w[e],     a0);
      a1 = __builtin_fmaf(xr[e + 1], w[e + 1], a1);
      a2 = __builtin_fmaf(xr[e + 2], w[e + 2], a2);
      a3 = __builtin_fmaf(xr[e + 3], w[e + 3], a3);
    }
    float p = ((a0 + a1) + (a2 + a3)) + b;
    out[(size_t)r * DDIM + lane] = __builtin_amdgcn_exp2f(sgn * p);
  }
}

// Grid: (SEQ/KT, SEQ/QT, BHX) = (8, 16, 16) = 2048 blocks, 256 threads.
// Per wave: 8 q rows x 64 k (lanes). Chunk-outer over d: 16 h-values live in
// VGPRs per chunk, vh recomputed per chunk (amortized over 8 q).
__global__ __launch_bounds__(256) void score_kernel(
    const float* __restrict__ eq,   // [BH*512][64]
    const float* __restrict__ hk,   // [BH*512][64]
    const float* __restrict__ Vw,   // [64]
    const float* __restrict__ Vb,   // [1]
    float* __restrict__ out)        // [BH,512,512]
{
  // Transposed k-tile [d][k], +1 pad: stage write bank=(lane)%32 (2/bank,
  // free); chunk read bank=(lane+j*65)%32 (2/bank, free).
  __shared__ float hk_l[64][65];

  const int bh   = blockIdx.z;
  const int q0   = blockIdx.y * QT;
  const int k0   = blockIdx.x * KT;
  const int lane = threadIdx.x & 63;
  const int wave = threadIdx.x >> 6;

  {  // wave stages k rows wave*16..wave*16+15; lane = d
    const float* base = hk + (size_t)(bh * SEQ + k0 + wave * 16) * DDIM;
#pragma unroll
    for (int r = 0; r < 16; ++r)
      hk_l[lane][wave * 16 + r] = base[r * DDIM + lane];
  }

  // acc0 = V_b + sum_d V_w[d]  (uniform)
  float acc0 = Vb[0];
#pragma unroll
  for (int d = 0; d < 64; ++d) acc0 += Vw[d];

  __syncthreads();

  float acc[8] = {0.f, 0.f, 0.f, 0.f, 0.f, 0.f, 0.f, 0.f};
  const int qbase =
      __builtin_amdgcn_readfirstlane((bh * SEQ + q0 + wave * 8) * DDIM);

#pragma unroll 1
  for (int c = 0; c < 4; ++c) {             // d-chunks of 16
    float h[16], vh[16];
#pragma unroll
    for (int j = 0; j < 16; ++j) h[j] = hk_l[c * 16 + j][lane];
#pragma unroll
    for (int j = 0; j < 16; ++j) vh[j] = Vw[c * 16 + j] * h[j];
    // Pin chunk values in VGPRs (R1 lesson: LLVM sinks cheap re-loads).
    asm volatile("" : "+v"(h[0]), "+v"(h[1]), "+v"(h[2]), "+v"(h[3]),
                      "+v"(h[4]), "+v"(h[5]), "+v"(h[6]), "+v"(h[7]));
    asm volatile("" : "+v"(h[8]),  "+v"(h[9]),  "+v"(h[10]), "+v"(h[11]),
                      "+v"(h[12]), "+v"(h[13]), "+v"(h[14]), "+v"(h[15]));
    asm volatile("" : "+v"(vh[0]), "+v"(vh[1]), "+v"(vh[2]), "+v"(vh[3]),
                      "+v"(vh[4]), "+v"(vh[5]), "+v"(vh[6]), "+v"(vh[7]));
    asm volatile("" : "+v"(vh[8]),  "+v"(vh[9]),  "+v"(vh[10]), "+v"(vh[11]),
                      "+v"(vh[12]), "+v"(vh[13]), "+v"(vh[14]), "+v"(vh[15]));

#pragma unroll 2
    for (int qi = 0; qi < 8; ++qi) {
      const float* qr = eq + qbase + qi * DDIM + c * 16;  // uniform -> s_load
      float a = 0.f;
#pragma unroll
      for (int p = 0; p < 8; ++p) {
        const float A = h[2*p]     + qr[2*p];
        const float B = h[2*p + 1] + qr[2*p + 1];
        const float num = __builtin_fmaf(vh[2*p + 1], A, vh[2*p] * B);
        a = __builtin_fmaf(num, __builtin_amdgcn_rcpf(A * B), a);
      }
      acc[qi] += a;
    }
  }

#pragma unroll
  for (int qi = 0; qi < 8; ++qi) {
    const size_t ob =
        (size_t)(bh * SEQ + q0 + wave * 8 + qi) * SEQ + k0 + lane;
    out[ob] = __builtin_fmaf(-2.f, acc[qi], acc0);
  }
}

extern "C" void kernel_launch(void* const* d_in, const int* in_sizes, int n_in,
                              void* d_out, int out_size, void* d_ws, size_t ws_size,
                              hipStream_t stream) {
  const float* query = (const float*)d_in[0];  // [2,8,512,64]
  const float* keys  = (const float*)d_in[1];  // [2,8,512,64]
  const float* Wa_w  = (const float*)d_in[2];  // [64,64]
  const float* Wa_b  = (const float*)d_in[3];  // [64]
  const float* Ua_w  = (const float*)d_in[4];  // [64,64]
  const float* Ua_b  = (const float*)d_in[5];  // [64]
  const float* V_w   = (const float*)d_in[6];  // [64]
  const float* V_b   = (const float*)d_in[7];  // [1]
  float* out = (float*)d_out;

  const int R = BHX * SEQ;                 // 8192 rows each side
  float* eq = (float*)d_ws;                // 2 MiB
  float* hk = eq + (size_t)R * DDIM;       // 2 MiB

  proj_kernel<<<1024, 256, 0, stream>>>(query, keys, Wa_w, Wa_b,
                                        Ua_w, Ua_b, eq, hk);

  dim3 grid(SEQ / KT, SEQ / QT, BHX);      // (8, 16, 16) = 2048 blocks
  score_kernel<<<grid, 256, 0, stream>>>(eq, hk, V_w, V_b, out);
}